// Round 5
// baseline (408.748 us; speedup 1.0000x reference)
//
#include <hip/hip_runtime.h>
#include <stdint.h>

typedef unsigned short u16;
typedef unsigned int   u32;
typedef short bf16x8 __attribute__((ext_vector_type(8)));   // 8 bf16 in 4 VGPRs
typedef u16   u16x8  __attribute__((ext_vector_type(8)));
typedef float f32x4  __attribute__((ext_vector_type(4)));

#define B_   2
#define S_   2048
#define HQ_  32
#define HKV_ 8
#define D_   128
#define SCALE 0.08838834764831845f   // 1/sqrt(128), fixed by problem shape

// workspace (bf16 elems, 16.8 MB): Kr [B][HKV][S][D] roped K; Vt [B][HKV][D][S]
#define KR_ELEMS (B_*HKV_*S_*D_)

#define NK_T (B_*S_*HKV_*64)        // one thread per K rope pair
#define NV_T (B_*HKV_*16*(S_/2))    // one thread per 2x8 V-transpose micro-tile

__device__ __forceinline__ float b2f(u16 x) { return __uint_as_float(((u32)x) << 16); }
__device__ __forceinline__ u16 f2b(float f) {
  u32 u = __float_as_uint(f);
  return (u16)((u + 0x7FFFu + ((u >> 16) & 1u)) >> 16);   // RTNE
}
// dtype probe: cos[0][0]=1.0 -> f32 word 0x3F800000; bf16-packed pair 0x3F803F80
// (round 3 proved behaviorally that the f32 branch is the live one)
__device__ __forceinline__ bool is_f32(const void* cs) {
  return ((const u32*)cs)[0] == 0x3F800000u;
}

__device__ __forceinline__ void gload16(const u16* g, u16* l) {
  // async global->LDS, 16B/lane; lane L's lds ptr = wave base + 16*L (HW rule)
  __builtin_amdgcn_global_load_lds(
      (const __attribute__((address_space(1))) u32*)g,
      (__attribute__((address_space(3))) u32*)l, 16, 0, 0);
}

// ---------------- pre-pass: RoPE(K) -> Kr, transpose(V) -> Vt (both bf16) ----
__global__ __launch_bounds__(256) void rope_pre(
    const void* __restrict__ kin, const void* __restrict__ vin,
    const void* __restrict__ cs, const void* __restrict__ sn, u16* __restrict__ ws)
{
  const bool f32 = is_f32(cs);
  int tid = blockIdx.x * 256 + threadIdx.x;
  if (tid < NK_T) {
    int d2 = tid & 63;
    int s  = (tid >> 6) & (S_ - 1);
    int h  = (tid >> 17) & (HKV_ - 1);
    int b  = tid >> 20;
    int gi = ((b*S_ + s)*HKV_ + h)*D_ + d2;
    int ci = s*D_ + d2;
    float xa, xb, c, si;
    if (f32) {
      const float* kf = (const float*)kin;
      xa = kf[gi]; xb = kf[gi + 64];
      c  = ((const float*)cs)[ci]; si = ((const float*)sn)[ci];
    } else {
      const u16* kb = (const u16*)kin;
      xa = b2f(kb[gi]); xb = b2f(kb[gi + 64]);
      c  = b2f(((const u16*)cs)[ci]); si = b2f(((const u16*)sn)[ci]);
    }
    int oi = ((b*HKV_ + h)*S_ + s)*D_ + d2;       // cos[d]==cos[d+64] by construction
    ws[oi]      = f2b(xa*c - xb*si);
    ws[oi + 64] = f2b(xb*c + xa*si);
  } else {
    // V transpose: rows s=2sp,2sp+1, cols [8c,8c+8); pack s-pairs into dwords.
    int t3   = tid - NK_T;
    int spLo = t3 & 15;
    int c4   = (t3 >> 4) & 15;
    int spHi = (t3 >> 8) & 63;
    int h    = (t3 >> 14) & (HKV_ - 1);
    int b    = t3 >> 17;
    int sp   = spHi*16 + spLo;
    int gi0  = ((b*S_ + 2*sp)*HKV_ + h)*D_ + 8*c4;
    u16 e0[8], e1[8];
    if (f32) {
      const float* vf = (const float*)vin;
      f32x4 a0 = *(const f32x4*)(vf + gi0);
      f32x4 a1 = *(const f32x4*)(vf + gi0 + 4);
      f32x4 b0 = *(const f32x4*)(vf + gi0 + HKV_*D_);
      f32x4 b1 = *(const f32x4*)(vf + gi0 + HKV_*D_ + 4);
#pragma unroll
      for (int j = 0; j < 4; ++j) {
        e0[j] = f2b(a0[j]); e0[4+j] = f2b(a1[j]);
        e1[j] = f2b(b0[j]); e1[4+j] = f2b(b1[j]);
      }
    } else {
      const u16* vb = (const u16*)vin;
      u16x8 v0 = *(const u16x8*)(vb + gi0);
      u16x8 v1 = *(const u16x8*)(vb + gi0 + HKV_*D_);
#pragma unroll
      for (int j = 0; j < 8; ++j) { e0[j] = v0[j]; e1[j] = v1[j]; }
    }
    u32* vtd = (u32*)(ws + KR_ELEMS);
    int rowbase = (b*HKV_ + h)*D_ + 8*c4;
#pragma unroll
    for (int j = 0; j < 8; ++j)
      vtd[(rowbase + j)*(S_/2) + sp] = (u32)e0[j] | ((u32)e1[j] << 16);
  }
}

// ---------------- flash attention ----------------
// 2048 blocks x 4 waves; wave w owns query rows q0+w*16..+15; BLOCK_N=32.
// ROUND 5 CHANGE: output is float32 (reference's output dtype). Staging back
// to global_load_lds (rounds 3/4 proved both staging paths bit-identical).
__global__ __launch_bounds__(256, 2) void flash_attn(
    const void* __restrict__ qg, const void* __restrict__ cs, const void* __restrict__ sn,
    const u16* __restrict__ ws, float* __restrict__ out)
{
  // LDS (u16): K tile [4][32][32] @0, Vt tile [128][32] @4096,
  //            Q tile [4][64][32] @0 (overlaps, consumed pre-loop), P @8192.
  __shared__ __attribute__((aligned(16))) u16 lds[10240];

  const bool f32 = is_f32(cs);
  const int t = threadIdx.x;
  const int lane = t & 63, w = t >> 6;
  const int lq = lane & 15, quad = lane >> 4;

  // XCD swizzle: bx%8 = XCD; 2 (b,kvh) combos per XCD -> K/V set fits its L2.
  int bx = blockIdx.x;
  int g = bx & 7, ii = bx >> 3;
  int combo = g*2 + (ii >> 7);
  int b = combo >> 3, kvh = combo & 7;
  int rr = ii & 127;
  int h  = kvh*4 + (rr & 3);     // GQA: q-head h uses kv-head h/4
  int qb = rr >> 2;
  int q0 = qb * 64;

  const u16* Kr = ws + (b*HKV_ + kvh)*S_*D_;
  const u16* Vt = ws + KR_ELEMS + (b*HKV_ + kvh)*D_*S_;

  // ---- stage Q tile with RoPE applied, chunk-major [c][m][32] ----
#pragma unroll
  for (int it = 0; it < 2; ++it) {
    int tp = it*256 + t;
    int row = tp >> 3, j = tp & 7;          // 8 threads/row, 16B vec loads
    int qbase = ((b*S_ + q0 + row)*HQ_ + h)*D_ + 8*j;
    int cbase = (q0 + row)*D_ + 8*j;
    float a[8], bb[8], cc[8], ssv[8];
    if (f32) {
      const float* qf32 = (const float*)qg;
      f32x4 a0 = *(const f32x4*)(qf32 + qbase);
      f32x4 a1 = *(const f32x4*)(qf32 + qbase + 4);
      f32x4 b0 = *(const f32x4*)(qf32 + qbase + 64);
      f32x4 b1 = *(const f32x4*)(qf32 + qbase + 68);
      f32x4 c0 = *(const f32x4*)((const float*)cs + cbase);
      f32x4 c1 = *(const f32x4*)((const float*)cs + cbase + 4);
      f32x4 s0 = *(const f32x4*)((const float*)sn + cbase);
      f32x4 s1 = *(const f32x4*)((const float*)sn + cbase + 4);
#pragma unroll
      for (int e = 0; e < 4; ++e) {
        a[e] = a0[e];  a[4+e] = a1[e];  bb[e] = b0[e]; bb[4+e] = b1[e];
        cc[e] = c0[e]; cc[4+e] = c1[e]; ssv[e] = s0[e]; ssv[4+e] = s1[e];
      }
    } else {
      const u16* qb16 = (const u16*)qg;
      u16x8 xa = *(const u16x8*)(qb16 + qbase);
      u16x8 xb = *(const u16x8*)(qb16 + qbase + 64);
      u16x8 cv = *(const u16x8*)((const u16*)cs + cbase);
      u16x8 sv = *(const u16x8*)((const u16*)sn + cbase);
#pragma unroll
      for (int e = 0; e < 8; ++e) {
        a[e] = b2f(xa[e]); bb[e] = b2f(xb[e]);
        cc[e] = b2f(cv[e]); ssv[e] = b2f(sv[e]);
      }
    }
    u16 o0[8], o1[8];
#pragma unroll
    for (int e = 0; e < 8; ++e) {
      o0[e] = f2b(a[e]*cc[e] - bb[e]*ssv[e]);   // d = 8j+e
      o1[e] = f2b(bb[e]*cc[e] + a[e]*ssv[e]);   // d = 64+8j+e (cos/sin repeat)
    }
    int c0 = j >> 2, e0 = (j & 3) * 8;
    *(u16x8*)&lds[c0*2048 + row*32 + e0]       = *(u16x8*)o0;
    *(u16x8*)&lds[(c0 + 2)*2048 + row*32 + e0] = *(u16x8*)o1;
  }
  __syncthreads();
  bf16x8 qf[4];
#pragma unroll
  for (int c = 0; c < 4; ++c)
    qf[c] = *(const bf16x8*)&lds[c*2048 + (w*16 + lq)*32 + quad*8];

  f32x4 o[8];
#pragma unroll
  for (int dt = 0; dt < 8; ++dt) o[dt] = (f32x4){0.f, 0.f, 0.f, 0.f};
  float m_i[4], l_i[4];
#pragma unroll
  for (int r = 0; r < 4; ++r) { m_i[r] = -1e30f; l_i[r] = 0.f; }

  const int nkb = 2*qb + 2;   // causal: keys [0, q0+64)
  for (int kb = 0; kb < nkb; ++kb) {
    const int n0 = kb * 32;
    __syncthreads();   // prior iter's LDS readers done (also frees Q region)
    // K tile chunk-major [c][n][32]
#pragma unroll
    for (int it = 0; it < 2; ++it) {
      int flat = (t + it*256) * 8;
      int c = flat >> 10, n = (flat >> 5) & 31, e = flat & 31;
      gload16(Kr + (n0 + n)*D_ + c*32 + e, &lds[flat]);
    }
    // Vt tile [d][n]
#pragma unroll
    for (int it = 0; it < 2; ++it) {
      int flat = (t + it*256) * 8;
      int d = flat >> 5, n = flat & 31;
      gload16(Vt + d*S_ + n0 + n, &lds[4096 + flat]);
    }
    __syncthreads();   // drains vmcnt: staged data visible to all waves

    // ---- S = Q K^T (two 16-col tiles) ----
    f32x4 sc0 = {0,0,0,0}, sc1 = {0,0,0,0};
#pragma unroll
    for (int c = 0; c < 4; ++c) {
      bf16x8 k0 = *(const bf16x8*)&lds[c*1024 + lq*32 + quad*8];
      bf16x8 k1 = *(const bf16x8*)&lds[c*1024 + (16 + lq)*32 + quad*8];
      sc0 = __builtin_amdgcn_mfma_f32_16x16x32_bf16(qf[c], k0, sc0, 0, 0, 0);
      sc1 = __builtin_amdgcn_mfma_f32_16x16x32_bf16(qf[c], k1, sc1, 0, 0, 0);
    }

    // ---- online softmax; C-layout row (quad*4+r) spans one 16-lane group ----
    const int kc = n0 + lq;
    float pv0[4], pv1[4], alpha[4];
#pragma unroll
    for (int r = 0; r < 4; ++r) {
      int qrow = q0 + w*16 + quad*4 + r;
      float s0 = (kc      <= qrow) ? sc0[r]*SCALE : -1e30f;
      float s1 = (kc + 16 <= qrow) ? sc1[r]*SCALE : -1e30f;
      float mx = fmaxf(s0, s1);
      mx = fmaxf(mx, __shfl_xor(mx, 1));
      mx = fmaxf(mx, __shfl_xor(mx, 2));
      mx = fmaxf(mx, __shfl_xor(mx, 4));
      mx = fmaxf(mx, __shfl_xor(mx, 8));
      float mn = fmaxf(m_i[r], mx);      // finite from kb=0 (key 0 always live)
      float al = __expf(m_i[r] - mn);
      float p0 = __expf(s0 - mn);        // args <= 0 always
      float p1 = __expf(s1 - mn);
      float rs = p0 + p1;
      rs += __shfl_xor(rs, 1);
      rs += __shfl_xor(rs, 2);
      rs += __shfl_xor(rs, 4);
      rs += __shfl_xor(rs, 8);
      l_i[r] = l_i[r]*al + rs;
      m_i[r] = mn;
      alpha[r] = al;
      pv0[r] = p0; pv1[r] = p1;
    }
#pragma unroll
    for (int dt = 0; dt < 8; ++dt) {
#pragma unroll
      for (int r = 0; r < 4; ++r) o[dt][r] *= alpha[r];
    }

    // ---- P: C-layout -> A-layout via per-wave LDS tile (intra-wave) ----
    u16* pw = &lds[8192 + w*512];
#pragma unroll
    for (int r = 0; r < 4; ++r) {
      pw[(quad*4 + r)*32 + lq]      = f2b(pv0[r]);
      pw[(quad*4 + r)*32 + 16 + lq] = f2b(pv1[r]);
    }
    asm volatile("s_waitcnt lgkmcnt(0)" ::: "memory");
    bf16x8 pf = *(const bf16x8*)&pw[lq*32 + quad*8];

    // ---- O += P V ----
#pragma unroll
    for (int dt = 0; dt < 8; ++dt) {
      bf16x8 vf = *(const bf16x8*)&lds[4096 + (dt*16 + lq)*32 + quad*8];
      o[dt] = __builtin_amdgcn_mfma_f32_16x16x32_bf16(pf, vf, o[dt], 0, 0, 0);
    }
  }

  // ---- epilogue: O / l, write [B][S][HQ][D] as FLOAT32 (reference dtype) ----
  float inv[4];
#pragma unroll
  for (int r = 0; r < 4; ++r) inv[r] = 1.0f / l_i[r];
#pragma unroll
  for (int dt = 0; dt < 8; ++dt) {
#pragma unroll
    for (int r = 0; r < 4; ++r) {
      int srow = q0 + w*16 + quad*4 + r;
      out[((b*S_ + srow)*HQ_ + h)*D_ + dt*16 + lq] = o[dt][r]*inv[r];
    }
  }
}

extern "C" void kernel_launch(void* const* d_in, const int* in_sizes, int n_in,
                              void* d_out, int out_size, void* d_ws, size_t ws_size,
                              hipStream_t stream) {
  const void* q  = d_in[0];
  const void* k  = d_in[1];
  const void* v  = d_in[2];
  const void* cs = d_in[3];
  const void* sn = d_in[4];
  // d_in[5] (mask) and d_in[6] (scale) are applied analytically in-kernel.
  u16*   ws  = (u16*)d_ws;     // needs 16.8 MB
  float* out = (float*)d_out;  // reference output dtype is float32

  const int npre = (NK_T + NV_T) / 256;   // 9216 blocks
  rope_pre<<<npre, 256, 0, stream>>>(k, v, cs, sn, ws);
  flash_attn<<<B_*HQ_*(S_/64), 256, 0, stream>>>(q, cs, sn, ws, out);
}

// Round 6
// 296.383 us; speedup vs baseline: 1.3791x; 1.3791x over previous
//
#include <hip/hip_runtime.h>
#include <stdint.h>

typedef unsigned short u16;
typedef unsigned int   u32;
typedef short bf16x8 __attribute__((ext_vector_type(8)));   // 8 bf16 in 4 VGPRs
typedef u16   u16x8  __attribute__((ext_vector_type(8)));
typedef float f32x4  __attribute__((ext_vector_type(4)));

#define B_   2
#define S_   2048
#define HQ_  32
#define HKV_ 8
#define D_   128
#define SCALE 0.08838834764831845f   // 1/sqrt(128), fixed by problem shape

// workspace (bf16 elems, 16.8 MB): Kr [B][HKV][S][D] roped K; Vt [B][HKV][D][S]
#define KR_ELEMS (B_*HKV_*S_*D_)

#define NK_T (B_*S_*HKV_*64)        // one thread per K rope pair
#define NV_T (B_*HKV_*16*(S_/2))    // one thread per 2x8 V-transpose micro-tile

__device__ __forceinline__ float b2f(u16 x) { return __uint_as_float(((u32)x) << 16); }
__device__ __forceinline__ u16 f2b(float f) {
  u32 u = __float_as_uint(f);
  return (u16)((u + 0x7FFFu + ((u >> 16) & 1u)) >> 16);   // RTNE
}
// dtype probe: cos[0][0]=1.0 -> f32 word 0x3F800000 (f32 branch proven live r3/r5)
__device__ __forceinline__ bool is_f32(const void* cs) {
  return ((const u32*)cs)[0] == 0x3F800000u;
}

__device__ __forceinline__ void gload16(const u16* g, u16* l) {
  __builtin_amdgcn_global_load_lds(
      (const __attribute__((address_space(1))) u32*)g,
      (__attribute__((address_space(3))) u32*)l, 16, 0, 0);
}

// ---------------- pre-pass: RoPE(K) -> Kr, transpose(V) -> Vt (both bf16) ----
__global__ __launch_bounds__(256) void rope_pre(
    const void* __restrict__ kin, const void* __restrict__ vin,
    const void* __restrict__ cs, const void* __restrict__ sn, u16* __restrict__ ws)
{
  const bool f32 = is_f32(cs);
  int tid = blockIdx.x * 256 + threadIdx.x;
  if (tid < NK_T) {
    int d2 = tid & 63;
    int s  = (tid >> 6) & (S_ - 1);
    int h  = (tid >> 17) & (HKV_ - 1);
    int b  = tid >> 20;
    int gi = ((b*S_ + s)*HKV_ + h)*D_ + d2;
    int ci = s*D_ + d2;
    float xa, xb, c, si;
    if (f32) {
      const float* kf = (const float*)kin;
      xa = kf[gi]; xb = kf[gi + 64];
      c  = ((const float*)cs)[ci]; si = ((const float*)sn)[ci];
    } else {
      const u16* kb = (const u16*)kin;
      xa = b2f(kb[gi]); xb = b2f(kb[gi + 64]);
      c  = b2f(((const u16*)cs)[ci]); si = b2f(((const u16*)sn)[ci]);
    }
    int oi = ((b*HKV_ + h)*S_ + s)*D_ + d2;       // cos[d]==cos[d+64]
    ws[oi]      = f2b(xa*c - xb*si);
    ws[oi + 64] = f2b(xb*c + xa*si);
  } else {
    int t3   = tid - NK_T;
    int spLo = t3 & 15;
    int c4   = (t3 >> 4) & 15;
    int spHi = (t3 >> 8) & 63;
    int h    = (t3 >> 14) & (HKV_ - 1);
    int b    = t3 >> 17;
    int sp   = spHi*16 + spLo;
    int gi0  = ((b*S_ + 2*sp)*HKV_ + h)*D_ + 8*c4;
    u16 e0[8], e1[8];
    if (f32) {
      const float* vf = (const float*)vin;
      f32x4 a0 = *(const f32x4*)(vf + gi0);
      f32x4 a1 = *(const f32x4*)(vf + gi0 + 4);
      f32x4 b0 = *(const f32x4*)(vf + gi0 + HKV_*D_);
      f32x4 b1 = *(const f32x4*)(vf + gi0 + HKV_*D_ + 4);
#pragma unroll
      for (int j = 0; j < 4; ++j) {
        e0[j] = f2b(a0[j]); e0[4+j] = f2b(a1[j]);
        e1[j] = f2b(b0[j]); e1[4+j] = f2b(b1[j]);
      }
    } else {
      const u16* vb = (const u16*)vin;
      u16x8 v0 = *(const u16x8*)(vb + gi0);
      u16x8 v1 = *(const u16x8*)(vb + gi0 + HKV_*D_);
#pragma unroll
      for (int j = 0; j < 8; ++j) { e0[j] = v0[j]; e1[j] = v1[j]; }
    }
    u32* vtd = (u32*)(ws + KR_ELEMS);
    int rowbase = (b*HKV_ + h)*D_ + 8*c4;
#pragma unroll
    for (int j = 0; j < 8; ++j)
      vtd[(rowbase + j)*(S_/2) + sp] = (u32)e0[j] | ((u32)e1[j] << 16);
  }
}

// ---------------- flash attention, S^T formulation ----------------
// 1024 blocks x 4 waves; each block processes Q-tiles {qbp, 31-qbp} (uniform
// 68 iters -> no tail). Wave w owns query rows q0+w*16..+15; query = lane&15
// (a COLUMN of S^T), so softmax reductions are 2 shuffles and m/l/alpha are
// per-lane scalars. O accumulates transposed; P^T goes through a padded
// stride-80B LDS tile with conflict-free b64 writes / b128 reads.
__global__ __launch_bounds__(256, 4) void flash_attn(
    const void* __restrict__ qg, const void* __restrict__ cs, const void* __restrict__ sn,
    const u16* __restrict__ ws, float* __restrict__ out)
{
  // LDS (u16): K [4][32][32] @0 (8KB), Vt [128][32] @4096 (8KB),
  //            Q [4][64][32] @0 (16KB, overlaps K+V, consumed pre-loop),
  //            P^T 4 waves x [16 q][40] @8192 (5KB; 32 keys + 8 pad)
  __shared__ __attribute__((aligned(16))) u16 lds[10752];

  const bool f32 = is_f32(cs);
  const int t = threadIdx.x;
  const int lane = t & 63, w = t >> 6;
  const int lq = lane & 15, quad = lane >> 4;

  // XCD swizzle: bx%8 = XCD; 2 (b,kvh) combos per XCD.
  int bx = blockIdx.x;               // 1024 blocks
  int g = bx & 7, ii = bx >> 3;      // ii: 0..127
  int combo = g*2 + (ii >> 6);
  int b = combo >> 3, kvh = combo & 7;
  int rr = ii & 63;
  int h   = kvh*4 + (rr & 3);        // GQA: q-head h uses kv-head h/4
  int qbp = rr >> 2;                 // 0..15

  const u16* Kr = ws + (b*HKV_ + kvh)*S_*D_;
  const u16* Vt = ws + KR_ELEMS + (b*HKV_ + kvh)*D_*S_;

  for (int half = 0; half < 2; ++half) {
    int qb = half ? (31 - qbp) : qbp;
    int q0 = qb * 64;
    if (half) __syncthreads();   // prior inner-loop LDS readers done before Q restage

    // ---- stage Q tile with RoPE applied, chunk-major [c][m][32] ----
#pragma unroll
    for (int it = 0; it < 2; ++it) {
      int tp = it*256 + t;
      int row = tp >> 3, j = tp & 7;          // 8 threads/row, 16B loads
      int qbase = ((b*S_ + q0 + row)*HQ_ + h)*D_ + 8*j;
      int cbase = (q0 + row)*D_ + 8*j;
      float a[8], bb[8], cc[8], ssv[8];
      if (f32) {
        const float* qf32 = (const float*)qg;
        f32x4 a0 = *(const f32x4*)(qf32 + qbase);
        f32x4 a1 = *(const f32x4*)(qf32 + qbase + 4);
        f32x4 b0 = *(const f32x4*)(qf32 + qbase + 64);
        f32x4 b1 = *(const f32x4*)(qf32 + qbase + 68);
        f32x4 c0 = *(const f32x4*)((const float*)cs + cbase);
        f32x4 c1 = *(const f32x4*)((const float*)cs + cbase + 4);
        f32x4 s0 = *(const f32x4*)((const float*)sn + cbase);
        f32x4 s1 = *(const f32x4*)((const float*)sn + cbase + 4);
#pragma unroll
        for (int e = 0; e < 4; ++e) {
          a[e] = a0[e];  a[4+e] = a1[e];  bb[e] = b0[e]; bb[4+e] = b1[e];
          cc[e] = c0[e]; cc[4+e] = c1[e]; ssv[e] = s0[e]; ssv[4+e] = s1[e];
        }
      } else {
        const u16* qb16 = (const u16*)qg;
        u16x8 xa = *(const u16x8*)(qb16 + qbase);
        u16x8 xb = *(const u16x8*)(qb16 + qbase + 64);
        u16x8 cv = *(const u16x8*)((const u16*)cs + cbase);
        u16x8 sv = *(const u16x8*)((const u16*)sn + cbase);
#pragma unroll
        for (int e = 0; e < 8; ++e) {
          a[e] = b2f(xa[e]); bb[e] = b2f(xb[e]);
          cc[e] = b2f(cv[e]); ssv[e] = b2f(sv[e]);
        }
      }
      u16 o0[8], o1[8];
#pragma unroll
      for (int e = 0; e < 8; ++e) {
        o0[e] = f2b(a[e]*cc[e] - bb[e]*ssv[e]);   // d = 8j+e
        o1[e] = f2b(bb[e]*cc[e] + a[e]*ssv[e]);   // d = 64+8j+e
      }
      int c0 = j >> 2, e0 = (j & 3) * 8;
      *(u16x8*)&lds[c0*2048 + row*32 + e0]       = *(u16x8*)o0;
      *(u16x8*)&lds[(c0 + 2)*2048 + row*32 + e0] = *(u16x8*)o1;
    }
    __syncthreads();
    bf16x8 qf[4];
#pragma unroll
    for (int c = 0; c < 4; ++c)
      qf[c] = *(const bf16x8*)&lds[c*2048 + (w*16 + lq)*32 + quad*8];

    f32x4 o[8];
#pragma unroll
    for (int dt = 0; dt < 8; ++dt) o[dt] = (f32x4){0.f, 0.f, 0.f, 0.f};
    float m_i = -1e30f, l_i = 0.f;
    const int qrow = q0 + w*16 + lq;       // this lane's query row

    const int nkb = 2*qb + 2;              // causal: keys [0, q0+64)
    for (int kb = 0; kb < nkb; ++kb) {
      const int n0 = kb * 32;
      __syncthreads();   // prior iter's LDS readers done (also frees Q region)
#pragma unroll
      for (int it = 0; it < 2; ++it) {     // K tile chunk-major [c][n][32]
        int flat = (t + it*256) * 8;
        int c = flat >> 10, n = (flat >> 5) & 31, e = flat & 31;
        gload16(Kr + (n0 + n)*D_ + c*32 + e, &lds[flat]);
      }
#pragma unroll
      for (int it = 0; it < 2; ++it) {     // Vt tile [d][n]
        int flat = (t + it*256) * 8;
        int d = flat >> 5, n = flat & 31;
        gload16(Vt + d*S_ + n0 + n, &lds[4096 + flat]);
      }
      __syncthreads();   // drains vmcnt: staged data visible

      // ---- S^T = K Q^T (two 16-key tiles; D rows = keys, cols = queries) ----
      f32x4 sc0 = {0,0,0,0}, sc1 = {0,0,0,0};
#pragma unroll
      for (int c = 0; c < 4; ++c) {
        bf16x8 k0 = *(const bf16x8*)&lds[c*1024 + lq*32 + quad*8];
        bf16x8 k1 = *(const bf16x8*)&lds[c*1024 + (16 + lq)*32 + quad*8];
        sc0 = __builtin_amdgcn_mfma_f32_16x16x32_bf16(k0, qf[c], sc0, 0, 0, 0);
        sc1 = __builtin_amdgcn_mfma_f32_16x16x32_bf16(k1, qf[c], sc1, 0, 0, 0);
      }

      // ---- online softmax: query = column lq -> per-lane scalars, 4 shuffles total
      const int kk = n0 + quad*4;          // this lane's reg-r key = kk + r (tile0)
      float s0[4], s1[4];
#pragma unroll
      for (int r = 0; r < 4; ++r) {
        s0[r] = (kk + r      <= qrow) ? sc0[r]*SCALE : -1e30f;
        s1[r] = (kk + 16 + r <= qrow) ? sc1[r]*SCALE : -1e30f;
      }
      float mx = fmaxf(fmaxf(fmaxf(s0[0], s0[1]), fmaxf(s0[2], s0[3])),
                       fmaxf(fmaxf(s1[0], s1[1]), fmaxf(s1[2], s1[3])));
      mx = fmaxf(mx, __shfl_xor(mx, 16));
      mx = fmaxf(mx, __shfl_xor(mx, 32));  // column max across the 4 quads
      float mn = fmaxf(m_i, mx);
      float al = __expf(m_i - mn);
      float p0[4], p1[4];
      float rs = 0.f;
#pragma unroll
      for (int r = 0; r < 4; ++r) {
        p0[r] = __expf(s0[r] - mn);
        p1[r] = __expf(s1[r] - mn);
        rs += p0[r] + p1[r];
      }
      rs += __shfl_xor(rs, 16);
      rs += __shfl_xor(rs, 32);
      l_i = l_i*al + rs;
      m_i = mn;
#pragma unroll
      for (int dt = 0; dt < 8; ++dt) {
#pragma unroll
        for (int r = 0; r < 4; ++r) o[dt][r] *= al;
      }

      // ---- P^T -> LDS: per-lane 4 consecutive u16 (keys kk..kk+3) per tile ----
      // row = query lq, stride 40 u16 (80B: conflict-free for b64 write & b128 read)
      u16* pw = &lds[8192 + w*640];
      u16 pk0[4], pk1[4];
#pragma unroll
      for (int r = 0; r < 4; ++r) { pk0[r] = f2b(p0[r]); pk1[r] = f2b(p1[r]); }
      *(uint64_t*)&pw[lq*40 + quad*4]      = *(uint64_t*)pk0;   // tile0 keys
      *(uint64_t*)&pw[lq*40 + 16 + quad*4] = *(uint64_t*)pk1;   // tile1 keys
      asm volatile("s_waitcnt lgkmcnt(0)" ::: "memory");        // intra-wave order
      bf16x8 pf = *(const bf16x8*)&pw[lq*40 + quad*8];          // keys quad*8..+7

      // ---- O^T += V^T P^T  (A = V^T rows d, B = P^T; same V reads as before) ----
#pragma unroll
      for (int dt = 0; dt < 8; ++dt) {
        bf16x8 vf = *(const bf16x8*)&lds[4096 + (dt*16 + lq)*32 + quad*8];
        o[dt] = __builtin_amdgcn_mfma_f32_16x16x32_bf16(vf, pf, o[dt], 0, 0, 0);
      }
    }

    // ---- epilogue: O^T/l -> out [B][S][HQ][D] f32; 4 consecutive d per lane ----
    float inv = 1.0f / l_i;
    float* op = out + ((b*S_ + qrow)*HQ_ + h)*D_ + quad*4;
#pragma unroll
    for (int dt = 0; dt < 8; ++dt) {
      f32x4 v = { o[dt][0]*inv, o[dt][1]*inv, o[dt][2]*inv, o[dt][3]*inv };
      *(f32x4*)(op + dt*16) = v;
    }
  }
}

extern "C" void kernel_launch(void* const* d_in, const int* in_sizes, int n_in,
                              void* d_out, int out_size, void* d_ws, size_t ws_size,
                              hipStream_t stream) {
  const void* q  = d_in[0];
  const void* k  = d_in[1];
  const void* v  = d_in[2];
  const void* cs = d_in[3];
  const void* sn = d_in[4];
  // d_in[5] (mask) and d_in[6] (scale) are applied analytically in-kernel.
  u16*   ws  = (u16*)d_ws;     // needs 16.8 MB
  float* out = (float*)d_out;  // reference output dtype is float32

  const int npre = (NK_T + NV_T) / 256;   // 9216 blocks
  rope_pre<<<npre, 256, 0, stream>>>(k, v, cs, sn, ws);
  flash_attn<<<B_*HQ_*(S_/128), 256, 0, stream>>>(q, cs, sn, ws, out);  // 1024
}